// Round 3
// baseline (1172.982 us; speedup 1.0000x reference)
//
#include <hip/hip_runtime.h>

#define NN 100000
#define NE 1200000
#define NPOS 100000
#define NNEG 100000

#define NBUCK ((NN + 255) / 256)    // 391 buckets of 256 nodes
#define BCAP 3712                   // mean 3070, sd ~55 -> 11.7 sigma margin
#define TILE 4096
#define EPT 16                      // edges per thread in bin_kernel

// ---------------- bucket build ----------------

__global__ __launch_bounds__(256) void zero_gcur_kernel(int* __restrict__ gcur) {
    int i = blockIdx.x * 256 + threadIdx.x;
    if (i < NBUCK) gcur[i] = 0;
}

// tile-synchronous multisplit: histogram in LDS, one global atomic per (tile,bucket)
__global__ __launch_bounds__(256) void bin_kernel(const int* __restrict__ src,
                                                  const int* __restrict__ dst,
                                                  int* __restrict__ gcur,
                                                  unsigned int* __restrict__ brec) {
    __shared__ int hcnt[NBUCK];
    __shared__ int hbase[NBUCK];
    for (int b = threadIdx.x; b < NBUCK; b += 256) hcnt[b] = 0;
    __syncthreads();

    const int tile0 = blockIdx.x * TILE;
    int bk[EPT];
    int rank[EPT];
    unsigned int rec[EPT];
#pragma unroll
    for (int i = 0; i < EPT; ++i) {
        int e = tile0 + i * 256 + threadIdx.x;
        if (e < NE) {
            int s = src[e];
            int d = dst[e];
            bk[i] = d >> 8;
            rec[i] = ((unsigned int)(d & 255) << 24) | (unsigned int)s;
            rank[i] = atomicAdd(&hcnt[bk[i]], 1);
        } else {
            bk[i] = -1;
        }
    }
    __syncthreads();
    for (int b = threadIdx.x; b < NBUCK; b += 256) {
        int h = hcnt[b];
        if (h > 0) hbase[b] = atomicAdd(&gcur[b], h);
    }
    __syncthreads();
#pragma unroll
    for (int i = 0; i < EPT; ++i) {
        if (bk[i] >= 0) {
            int p = hbase[bk[i]] + rank[i];
            if (p < BCAP) brec[(size_t)bk[i] * BCAP + p] = rec[i];
        }
    }
}

// per-bucket degree -> dis = rsqrt(deg_in + 1)
__global__ __launch_bounds__(256) void deg_kernel(const int* __restrict__ gcur,
                                                  const unsigned int* __restrict__ brec,
                                                  float* __restrict__ dis) {
    __shared__ int cnt[256];
    const int b = blockIdx.x;
    cnt[threadIdx.x] = 0;
    __syncthreads();
    const int n = min(gcur[b], BCAP);
    const unsigned int* rec = brec + (size_t)b * BCAP;
    for (int i = threadIdx.x; i < n; i += 256) {
        atomicAdd(&cnt[rec[i] >> 24], 1);
    }
    __syncthreads();
    int v = b * 256 + threadIdx.x;
    if (v < NN) dis[v] = rsqrtf((float)(cnt[threadIdx.x] + 1));
}

// ---------------- dense transform: H' = (relu?)(X) @ W  [* dis[row]] ----------------

template <bool RELU, bool SCALE>
__global__ __launch_bounds__(256) void gemm64_kernel(const float* __restrict__ X,
                                                     const float* __restrict__ W,
                                                     const float* __restrict__ dis,
                                                     float* __restrict__ Hout, int n) {
    __shared__ float xs[64][64];
    const int lane = threadIdx.x & 63;
    const int wid = threadIdx.x >> 6;

    float w[64];
#pragma unroll
    for (int k = 0; k < 64; ++k) w[k] = W[k * 64 + lane];

    const int row0 = blockIdx.x * 64;

#pragma unroll
    for (int i = 0; i < 16; ++i) {
        int idx = threadIdx.x + i * 256;
        int r = idx >> 6, c = idx & 63;
        int row = row0 + r;
        float v = 0.0f;
        if (row < n) v = X[(size_t)row * 64 + c];
        if (RELU) v = fmaxf(v, 0.0f);
        xs[r][c] = v;
    }
    __syncthreads();

#pragma unroll 1
    for (int rr = 0; rr < 16; ++rr) {
        int r = wid * 16 + rr;
        int row = row0 + r;
        if (row < n) {
            float acc = 0.0f;
#pragma unroll
            for (int k = 0; k < 64; ++k) acc += xs[r][k] * w[k];
            if (SCALE) acc *= dis[row];
            Hout[(size_t)row * 64 + lane] = acc;
        }
    }
}

// ---------------- bucketed aggregation ----------------
// Z[v] = dis[v]*(H'[v] + sum_{s->v} H'[s]) + bias ; H' pre-scaled by dis[src]
// one block per bucket; acc[256][64] in LDS (64 KB, 2 blocks/CU)

__global__ __launch_bounds__(512) void agg_kernel(const int* __restrict__ gcur,
                                                  const unsigned int* __restrict__ brec,
                                                  const float* __restrict__ dis,
                                                  const float* __restrict__ Hp,
                                                  const float* __restrict__ bias,
                                                  float* __restrict__ Z) {
    __shared__ float acc[256 * 64];  // 64 KB
    const int b = blockIdx.x;
    const int lane = threadIdx.x & 63;
    const int wid = threadIdx.x >> 6;  // 0..7

    // zero accumulators (float4)
    float4* acc4 = reinterpret_cast<float4*>(acc);
#pragma unroll
    for (int i = 0; i < 8; ++i) acc4[threadIdx.x + i * 512] = make_float4(0.f, 0.f, 0.f, 0.f);
    __syncthreads();

    const int n = min(gcur[b], BCAP);
    const unsigned int* rec = brec + (size_t)b * BCAP;

    // 2-deep pipelined edge gather: wave handles e, e+8 per iteration
    for (int e = wid; e < n; e += 16) {
        unsigned int r0 = rec[e];
        const bool has1 = (e + 8) < n;
        unsigned int r1 = has1 ? rec[e + 8] : 0u;
        int s0 = r0 & 0xFFFFFF;
        int d0 = r0 >> 24;
        float v0 = Hp[(size_t)s0 * 64 + lane];
        int d1 = 0;
        float v1 = 0.0f;
        if (has1) {
            int s1 = r1 & 0xFFFFFF;
            d1 = r1 >> 24;
            v1 = Hp[(size_t)s1 * 64 + lane];
        }
        atomicAdd(&acc[d0 * 64 + lane], v0);
        if (has1) atomicAdd(&acc[d1 * 64 + lane], v1);
    }
    __syncthreads();

    // epilogue: Z = (acc + H'self) * dis + bias
    const int v0 = b * 256;
    const float bl = bias[lane];
    for (int r = wid; r < 256; r += 8) {
        int v = v0 + r;
        if (v < NN) {
            float z = (acc[r * 64 + lane] + Hp[(size_t)v * 64 + lane]) * dis[v] + bl;
            Z[(size_t)v * 64 + lane] = z;
        }
    }
}

// ---------------- decoder ----------------

__global__ __launch_bounds__(256) void decode_kernel(const int* __restrict__ pos,
                                                     const int* __restrict__ neg,
                                                     const float* __restrict__ Z,
                                                     float* __restrict__ out) {
    const int lane = threadIdx.x & 63;
    const int pair = blockIdx.x * 4 + (threadIdx.x >> 6);
    if (pair >= NPOS + NNEG) return;
    int a, b;
    if (pair < NPOS) {
        a = pos[pair];
        b = pos[NPOS + pair];
    } else {
        int p = pair - NPOS;
        a = neg[p];
        b = neg[NNEG + p];
    }
    float v = Z[(size_t)a * 64 + lane] * Z[(size_t)b * 64 + lane];
#pragma unroll
    for (int off = 32; off > 0; off >>= 1) v += __shfl_down(v, off, 64);
    if (lane == 0) out[pair] = v;
}

// ---------------- fallback (round-0 atomic path) ----------------

__global__ __launch_bounds__(256) void init_deg_kernel(float* __restrict__ deg, int n) {
    int i = blockIdx.x * 256 + threadIdx.x;
    if (i < n) deg[i] = 1.0f;
}
__global__ __launch_bounds__(256) void deg_count_kernel(const int* __restrict__ dst,
                                                        float* __restrict__ deg, int e) {
    int i = blockIdx.x * 256 + threadIdx.x;
    if (i < e) atomicAdd(&deg[dst[i]], 1.0f);
}
__global__ __launch_bounds__(256) void dis_kernel(float* __restrict__ deg, int n) {
    int i = blockIdx.x * 256 + threadIdx.x;
    if (i < n) deg[i] = rsqrtf(deg[i]);
}
__global__ __launch_bounds__(256) void selfloop_init_kernel(const float* __restrict__ H,
                                                            const float* __restrict__ dis,
                                                            const float* __restrict__ b,
                                                            float* __restrict__ Z, int n) {
    int i = blockIdx.x * 256 + threadIdx.x;
    if (i < n * 16) {
        int v = i >> 4, c = i & 15;
        float d = dis[v], d2 = d * d;
        float4 h4 = reinterpret_cast<const float4*>(H)[i];
        float4 b4 = reinterpret_cast<const float4*>(b)[c];
        float4 z4;
        z4.x = b4.x + h4.x * d2;
        z4.y = b4.y + h4.y * d2;
        z4.z = b4.z + h4.z * d2;
        z4.w = b4.w + h4.w * d2;
        reinterpret_cast<float4*>(Z)[i] = z4;
    }
}
__global__ __launch_bounds__(256) void edge_agg_kernel(const int* __restrict__ src,
                                                       const int* __restrict__ dst,
                                                       const float* __restrict__ dis,
                                                       const float* __restrict__ H,
                                                       float* __restrict__ Z, int e) {
    const int lane = threadIdx.x & 63;
    const int edge = blockIdx.x * 4 + (threadIdx.x >> 6);
    if (edge < e) {
        int s = src[edge];
        int d = dst[edge];
        float nm = dis[s] * dis[d];
        float v = H[(size_t)s * 64 + lane] * nm;
        atomicAdd(&Z[(size_t)d * 64 + lane], v);
    }
}

// ---------------- launch ----------------

extern "C" void kernel_launch(void* const* d_in, const int* in_sizes, int n_in,
                              void* d_out, int out_size, void* d_ws, size_t ws_size,
                              hipStream_t stream) {
    const float* x   = (const float*)d_in[0];
    const int*   ei  = (const int*)d_in[1];
    const int*   pos = (const int*)d_in[2];
    const int*   neg = (const int*)d_in[3];
    const float* W1  = (const float*)d_in[4];
    const float* b1  = (const float*)d_in[5];
    const float* W2  = (const float*)d_in[6];
    const float* b2  = (const float*)d_in[7];
    float* out = (float*)d_out;

    const int* src = ei;
    const int* dst = ei + NE;

    char* ws = (char*)d_ws;
    size_t o = 0;
    auto alloc = [&](size_t bytes) {
        size_t p = o;
        o = (o + bytes + 255) & ~(size_t)255;
        return p;
    };
    float*        dis  = (float*)(ws + alloc((size_t)NN * 4));
    int*          gcur = (int*)(ws + alloc((size_t)NBUCK * 4));
    unsigned int* brec = (unsigned int*)(ws + alloc((size_t)NBUCK * BCAP * 4));
    float*        bufA = (float*)(ws + alloc((size_t)NN * 64 * 4));
    float*        bufB = (float*)(ws + alloc((size_t)NN * 64 * 4));

    if (o <= ws_size) {
        // ---- bucketed gather path ----
        zero_gcur_kernel<<<(NBUCK + 255) / 256, 256, 0, stream>>>(gcur);
        bin_kernel<<<(NE + TILE - 1) / TILE, 256, 0, stream>>>(src, dst, gcur, brec);
        deg_kernel<<<NBUCK, 256, 0, stream>>>(gcur, brec, dis);

        gemm64_kernel<false, true><<<(NN + 63) / 64, 256, 0, stream>>>(x, W1, dis, bufA, NN);
        agg_kernel<<<NBUCK, 512, 0, stream>>>(gcur, brec, dis, bufA, b1, bufB);

        gemm64_kernel<true, true><<<(NN + 63) / 64, 256, 0, stream>>>(bufB, W2, dis, bufA, NN);
        agg_kernel<<<NBUCK, 512, 0, stream>>>(gcur, brec, dis, bufA, b2, bufB);

        decode_kernel<<<((NPOS + NNEG) + 3) / 4, 256, 0, stream>>>(pos, neg, bufB, out);
    } else {
        // ---- fallback: atomic scatter path ----
        float* fdis = (float*)ws;
        size_t foff = ((size_t)NN * 4 + 255) / 256 * 256;
        float* fA = (float*)(ws + foff);
        float* fB = fA + (size_t)NN * 64;

        init_deg_kernel<<<(NN + 255) / 256, 256, 0, stream>>>(fdis, NN);
        deg_count_kernel<<<(NE + 255) / 256, 256, 0, stream>>>(dst, fdis, NE);
        dis_kernel<<<(NN + 255) / 256, 256, 0, stream>>>(fdis, NN);

        gemm64_kernel<false, false><<<(NN + 63) / 64, 256, 0, stream>>>(x, W1, nullptr, fA, NN);
        selfloop_init_kernel<<<(NN * 16 + 255) / 256, 256, 0, stream>>>(fA, fdis, b1, fB, NN);
        edge_agg_kernel<<<(NE + 3) / 4, 256, 0, stream>>>(src, dst, fdis, fA, fB, NE);

        gemm64_kernel<true, false><<<(NN + 63) / 64, 256, 0, stream>>>(fB, W2, nullptr, fA, NN);
        selfloop_init_kernel<<<(NN * 16 + 255) / 256, 256, 0, stream>>>(fA, fdis, b2, fB, NN);
        edge_agg_kernel<<<(NE + 3) / 4, 256, 0, stream>>>(src, dst, fdis, fA, fB, NE);

        decode_kernel<<<((NPOS + NNEG) + 3) / 4, 256, 0, stream>>>(pos, neg, fB, out);
    }
}

// Round 4
// 234.941 us; speedup vs baseline: 4.9927x; 4.9927x over previous
//
#include <hip/hip_runtime.h>

#define NN 100000
#define NE 1200000
#define NPOS 100000
#define NNEG 100000

#define NBUCK ((NN + 255) / 256)    // 391 buckets of 256 nodes
#define BCAP 3712                   // mean 3070, sd ~55 -> 11.7 sigma margin
#define TILE 4096
#define EPT 16                      // edges per thread in bin_kernel

// ---------------- stage 1: bin edges by dst bucket (dst>>8) ----------------
// tile-synchronous multisplit: histogram in LDS, one global atomic per (tile,bucket)

__global__ __launch_bounds__(256) void bin_kernel(const int* __restrict__ src,
                                                  const int* __restrict__ dst,
                                                  int* __restrict__ gcur,
                                                  unsigned int* __restrict__ brec) {
    __shared__ int hcnt[NBUCK];
    __shared__ int hbase[NBUCK];
    for (int b = threadIdx.x; b < NBUCK; b += 256) hcnt[b] = 0;
    __syncthreads();

    const int tile0 = blockIdx.x * TILE;
    int bk[EPT];
    int rank[EPT];
    unsigned int rec[EPT];
#pragma unroll
    for (int i = 0; i < EPT; ++i) {
        int e = tile0 + i * 256 + threadIdx.x;
        if (e < NE) {
            int s = src[e];
            int d = dst[e];
            bk[i] = d >> 8;
            rec[i] = ((unsigned int)(d & 255) << 24) | (unsigned int)s;
            rank[i] = atomicAdd(&hcnt[bk[i]], 1);
        } else {
            bk[i] = -1;
        }
    }
    __syncthreads();
    for (int b = threadIdx.x; b < NBUCK; b += 256) {
        int h = hcnt[b];
        if (h > 0) hbase[b] = atomicAdd(&gcur[b], h);
    }
    __syncthreads();
#pragma unroll
    for (int i = 0; i < EPT; ++i) {
        if (bk[i] >= 0) {
            int p = hbase[bk[i]] + rank[i];
            if (p < BCAP) brec[(size_t)bk[i] * BCAP + p] = rec[i];
        }
    }
}

// ---------------- stage 2: per-bucket sort by dstLocal -> CSR slice ----------------
// one block per bucket; all sorting in LDS; coalesced global writes.
// outputs: csr[b*BCAP + i] (src sorted by dstLocal), st[v], en[v], dis[v]

__global__ __launch_bounds__(256) void bucket_csr_kernel(const int* __restrict__ gcur,
                                                         const unsigned int* __restrict__ brec,
                                                         int* __restrict__ csr,
                                                         int* __restrict__ st,
                                                         int* __restrict__ en,
                                                         float* __restrict__ dis) {
    __shared__ int hist[256];
    __shared__ int scanv[256];
    __shared__ int cur[256];
    __shared__ int sorted[BCAP];
    const int b = blockIdx.x;
    const int t = threadIdx.x;
    const int n = min(gcur[b], BCAP);
    const unsigned int* rec = brec + (size_t)b * BCAP;

    hist[t] = 0;
    __syncthreads();
    for (int i = t; i < n; i += 256) atomicAdd(&hist[rec[i] >> 24], 1);
    __syncthreads();

    // inclusive scan (Hillis-Steele)
    int c = hist[t];
    scanv[t] = c;
    __syncthreads();
    for (int off = 1; off < 256; off <<= 1) {
        int add = (t >= off) ? scanv[t - off] : 0;
        __syncthreads();
        scanv[t] += add;
        __syncthreads();
    }
    int base = scanv[t] - c;  // exclusive
    cur[t] = base;
    __syncthreads();

    // scatter into dst-sorted order in LDS
    for (int i = t; i < n; i += 256) {
        unsigned int r = rec[i];
        int p = atomicAdd(&cur[r >> 24], 1);
        sorted[p] = (int)(r & 0xFFFFFF);
    }
    __syncthreads();

    // coalesced write-out
    for (int i = t; i < n; i += 256) csr[(size_t)b * BCAP + i] = sorted[i];

    int v = b * 256 + t;
    if (v < NN) {
        st[v] = b * BCAP + base;
        en[v] = b * BCAP + base + c;
        dis[v] = rsqrtf((float)(c + 1));  // in-degree + self-loop
    }
}

// ---------------- dense transform: H' = (relu?)(X) @ W  [* dis[row]] ----------------

template <bool RELU, bool SCALE>
__global__ __launch_bounds__(256) void gemm64_kernel(const float* __restrict__ X,
                                                     const float* __restrict__ W,
                                                     const float* __restrict__ dis,
                                                     float* __restrict__ Hout, int n) {
    __shared__ float xs[64][64];
    const int lane = threadIdx.x & 63;
    const int wid = threadIdx.x >> 6;

    float w[64];
#pragma unroll
    for (int k = 0; k < 64; ++k) w[k] = W[k * 64 + lane];

    const int row0 = blockIdx.x * 64;

#pragma unroll
    for (int i = 0; i < 16; ++i) {
        int idx = threadIdx.x + i * 256;
        int r = idx >> 6, c = idx & 63;
        int row = row0 + r;
        float v = 0.0f;
        if (row < n) v = X[(size_t)row * 64 + c];
        if (RELU) v = fmaxf(v, 0.0f);
        xs[r][c] = v;
    }
    __syncthreads();

#pragma unroll 1
    for (int rr = 0; rr < 16; ++rr) {
        int r = wid * 16 + rr;
        int row = row0 + r;
        if (row < n) {
            float acc = 0.0f;
#pragma unroll
            for (int k = 0; k < 64; ++k) acc += xs[r][k] * w[k];
            if (SCALE) acc *= dis[row];
            Hout[(size_t)row * 64 + lane] = acc;
        }
    }
}

// ---------------- gather aggregation: one wave per node, 4-deep pipeline ----------------
// Z[v] = dis[v]*(H'[v] + sum_in H'[s]) + bias

__global__ __launch_bounds__(256) void agg_kernel(const int* __restrict__ csr,
                                                  const int* __restrict__ st,
                                                  const int* __restrict__ en,
                                                  const float* __restrict__ dis,
                                                  const float* __restrict__ Hp,
                                                  const float* __restrict__ bias,
                                                  float* __restrict__ Z, int n) {
    const int lane = threadIdx.x & 63;
    int v = blockIdx.x * 4 + (threadIdx.x >> 6);
    if (v >= n) return;
    v = __builtin_amdgcn_readfirstlane(v);
    const int e0 = __builtin_amdgcn_readfirstlane(st[v]);
    const int e1 = __builtin_amdgcn_readfirstlane(en[v]);
    float a0 = Hp[(size_t)v * 64 + lane];  // self loop
    float a1 = 0.0f, a2 = 0.0f, a3 = 0.0f;
    int e = e0;
    for (; e + 4 <= e1; e += 4) {
        int s0 = csr[e];
        int s1 = csr[e + 1];
        int s2 = csr[e + 2];
        int s3 = csr[e + 3];
        a0 += Hp[(size_t)s0 * 64 + lane];
        a1 += Hp[(size_t)s1 * 64 + lane];
        a2 += Hp[(size_t)s2 * 64 + lane];
        a3 += Hp[(size_t)s3 * 64 + lane];
    }
    for (; e < e1; ++e) a1 += Hp[(size_t)csr[e] * 64 + lane];
    Z[(size_t)v * 64 + lane] = ((a0 + a1) + (a2 + a3)) * dis[v] + bias[lane];
}

// ---------------- decoder ----------------

__global__ __launch_bounds__(256) void decode_kernel(const int* __restrict__ pos,
                                                     const int* __restrict__ neg,
                                                     const float* __restrict__ Z,
                                                     float* __restrict__ out) {
    const int lane = threadIdx.x & 63;
    const int pair = blockIdx.x * 4 + (threadIdx.x >> 6);
    if (pair >= NPOS + NNEG) return;
    int a, b;
    if (pair < NPOS) {
        a = pos[pair];
        b = pos[NPOS + pair];
    } else {
        int p = pair - NPOS;
        a = neg[p];
        b = neg[NNEG + p];
    }
    float v = Z[(size_t)a * 64 + lane] * Z[(size_t)b * 64 + lane];
#pragma unroll
    for (int off = 32; off > 0; off >>= 1) v += __shfl_down(v, off, 64);
    if (lane == 0) out[pair] = v;
}

// ---------------- fallback (round-0 atomic path) ----------------

__global__ __launch_bounds__(256) void init_deg_kernel(float* __restrict__ deg, int n) {
    int i = blockIdx.x * 256 + threadIdx.x;
    if (i < n) deg[i] = 1.0f;
}
__global__ __launch_bounds__(256) void deg_count_kernel(const int* __restrict__ dst,
                                                        float* __restrict__ deg, int e) {
    int i = blockIdx.x * 256 + threadIdx.x;
    if (i < e) atomicAdd(&deg[dst[i]], 1.0f);
}
__global__ __launch_bounds__(256) void dis_kernel(float* __restrict__ deg, int n) {
    int i = blockIdx.x * 256 + threadIdx.x;
    if (i < n) deg[i] = rsqrtf(deg[i]);
}
__global__ __launch_bounds__(256) void selfloop_init_kernel(const float* __restrict__ H,
                                                            const float* __restrict__ dis,
                                                            const float* __restrict__ b,
                                                            float* __restrict__ Z, int n) {
    int i = blockIdx.x * 256 + threadIdx.x;
    if (i < n * 16) {
        int v = i >> 4, c = i & 15;
        float d = dis[v], d2 = d * d;
        float4 h4 = reinterpret_cast<const float4*>(H)[i];
        float4 b4 = reinterpret_cast<const float4*>(b)[c];
        float4 z4;
        z4.x = b4.x + h4.x * d2;
        z4.y = b4.y + h4.y * d2;
        z4.z = b4.z + h4.z * d2;
        z4.w = b4.w + h4.w * d2;
        reinterpret_cast<float4*>(Z)[i] = z4;
    }
}
__global__ __launch_bounds__(256) void edge_agg_kernel(const int* __restrict__ src,
                                                       const int* __restrict__ dst,
                                                       const float* __restrict__ dis,
                                                       const float* __restrict__ H,
                                                       float* __restrict__ Z, int e) {
    const int lane = threadIdx.x & 63;
    const int edge = blockIdx.x * 4 + (threadIdx.x >> 6);
    if (edge < e) {
        int s = src[edge];
        int d = dst[edge];
        float nm = dis[s] * dis[d];
        float v = H[(size_t)s * 64 + lane] * nm;
        atomicAdd(&Z[(size_t)d * 64 + lane], v);
    }
}

// ---------------- launch ----------------

extern "C" void kernel_launch(void* const* d_in, const int* in_sizes, int n_in,
                              void* d_out, int out_size, void* d_ws, size_t ws_size,
                              hipStream_t stream) {
    const float* x   = (const float*)d_in[0];
    const int*   ei  = (const int*)d_in[1];
    const int*   pos = (const int*)d_in[2];
    const int*   neg = (const int*)d_in[3];
    const float* W1  = (const float*)d_in[4];
    const float* b1  = (const float*)d_in[5];
    const float* W2  = (const float*)d_in[6];
    const float* b2  = (const float*)d_in[7];
    float* out = (float*)d_out;

    const int* src = ei;
    const int* dst = ei + NE;

    char* ws = (char*)d_ws;
    size_t o = 0;
    auto alloc = [&](size_t bytes) {
        size_t p = o;
        o = (o + bytes + 255) & ~(size_t)255;
        return p;
    };
    float*        dis  = (float*)(ws + alloc((size_t)NN * 4));
    int*          gcur = (int*)(ws + alloc((size_t)NBUCK * 4));
    unsigned int* brec = (unsigned int*)(ws + alloc((size_t)NBUCK * BCAP * 4));
    int*          csr  = (int*)(ws + alloc((size_t)NBUCK * BCAP * 4));
    int*          stA  = (int*)(ws + alloc((size_t)NN * 4));
    int*          enA  = (int*)(ws + alloc((size_t)NN * 4));
    float*        bufA = (float*)(ws + alloc((size_t)NN * 64 * 4));
    float*        bufB = (float*)(ws + alloc((size_t)NN * 64 * 4));

    if (o <= ws_size) {
        // ---- bucketed CSR gather path ----
        hipMemsetAsync(gcur, 0, (size_t)NBUCK * 4, stream);
        bin_kernel<<<(NE + TILE - 1) / TILE, 256, 0, stream>>>(src, dst, gcur, brec);
        bucket_csr_kernel<<<NBUCK, 256, 0, stream>>>(gcur, brec, csr, stA, enA, dis);

        gemm64_kernel<false, true><<<(NN + 63) / 64, 256, 0, stream>>>(x, W1, dis, bufA, NN);
        agg_kernel<<<(NN + 3) / 4, 256, 0, stream>>>(csr, stA, enA, dis, bufA, b1, bufB, NN);

        gemm64_kernel<true, true><<<(NN + 63) / 64, 256, 0, stream>>>(bufB, W2, dis, bufA, NN);
        agg_kernel<<<(NN + 3) / 4, 256, 0, stream>>>(csr, stA, enA, dis, bufA, b2, bufB, NN);

        decode_kernel<<<((NPOS + NNEG) + 3) / 4, 256, 0, stream>>>(pos, neg, bufB, out);
    } else {
        // ---- fallback: atomic scatter path ----
        float* fdis = (float*)ws;
        size_t foff = ((size_t)NN * 4 + 255) / 256 * 256;
        float* fA = (float*)(ws + foff);
        float* fB = fA + (size_t)NN * 64;

        init_deg_kernel<<<(NN + 255) / 256, 256, 0, stream>>>(fdis, NN);
        deg_count_kernel<<<(NE + 255) / 256, 256, 0, stream>>>(dst, fdis, NE);
        dis_kernel<<<(NN + 255) / 256, 256, 0, stream>>>(fdis, NN);

        gemm64_kernel<false, false><<<(NN + 63) / 64, 256, 0, stream>>>(x, W1, nullptr, fA, NN);
        selfloop_init_kernel<<<(NN * 16 + 255) / 256, 256, 0, stream>>>(fA, fdis, b1, fB, NN);
        edge_agg_kernel<<<(NE + 3) / 4, 256, 0, stream>>>(src, dst, fdis, fA, fB, NE);

        gemm64_kernel<true, false><<<(NN + 63) / 64, 256, 0, stream>>>(fB, W2, nullptr, fA, NN);
        selfloop_init_kernel<<<(NN * 16 + 255) / 256, 256, 0, stream>>>(fA, fdis, b2, fB, NN);
        edge_agg_kernel<<<(NE + 3) / 4, 256, 0, stream>>>(src, dst, fdis, fA, fB, NE);

        decode_kernel<<<((NPOS + NNEG) + 3) / 4, 256, 0, stream>>>(pos, neg, fB, out);
    }
}

// Round 5
// 215.404 us; speedup vs baseline: 5.4455x; 1.0907x over previous
//
#include <hip/hip_runtime.h>

#define NN 100000
#define NE 1200000
#define NPOS 100000
#define NNEG 100000

#define NBUCK ((NN + 255) / 256)    // 391 buckets of 256 nodes
#define BCAP 3712                   // mean 3070, sd ~55 -> 11.7 sigma margin
#define TILE 4096
#define EPT 16                      // edges per thread in bin_kernel

typedef unsigned short bf16_t;

__device__ __forceinline__ float bf2f(bf16_t b) {
    return __uint_as_float(((unsigned int)b) << 16);
}
__device__ __forceinline__ bf16_t f2bf(float f) {
    unsigned int u = __float_as_uint(f);
    u += 0x7FFFu + ((u >> 16) & 1u);  // round-to-nearest-even
    return (bf16_t)(u >> 16);
}

// ---------------- stage 1: bin edges by dst bucket (dst>>8) ----------------

__global__ __launch_bounds__(256) void bin_kernel(const int* __restrict__ src,
                                                  const int* __restrict__ dst,
                                                  int* __restrict__ gcur,
                                                  unsigned int* __restrict__ brec) {
    __shared__ int hcnt[NBUCK];
    __shared__ int hbase[NBUCK];
    for (int b = threadIdx.x; b < NBUCK; b += 256) hcnt[b] = 0;
    __syncthreads();

    const int tile0 = blockIdx.x * TILE;
    int bk[EPT];
    int rank[EPT];
    unsigned int rec[EPT];
#pragma unroll
    for (int i = 0; i < EPT; ++i) {
        int e = tile0 + i * 256 + threadIdx.x;
        if (e < NE) {
            int s = src[e];
            int d = dst[e];
            bk[i] = d >> 8;
            rec[i] = ((unsigned int)(d & 255) << 24) | (unsigned int)s;
            rank[i] = atomicAdd(&hcnt[bk[i]], 1);
        } else {
            bk[i] = -1;
        }
    }
    __syncthreads();
    for (int b = threadIdx.x; b < NBUCK; b += 256) {
        int h = hcnt[b];
        if (h > 0) hbase[b] = atomicAdd(&gcur[b], h);
    }
    __syncthreads();
#pragma unroll
    for (int i = 0; i < EPT; ++i) {
        if (bk[i] >= 0) {
            int p = hbase[bk[i]] + rank[i];
            if (p < BCAP) brec[(size_t)bk[i] * BCAP + p] = rec[i];
        }
    }
}

// ---------------- stage 2: per-bucket sort by dstLocal -> CSR slice ----------------

__global__ __launch_bounds__(256) void bucket_csr_kernel(const int* __restrict__ gcur,
                                                         const unsigned int* __restrict__ brec,
                                                         int* __restrict__ csr,
                                                         int* __restrict__ st,
                                                         int* __restrict__ en,
                                                         float* __restrict__ dis) {
    __shared__ int hist[256];
    __shared__ int scanv[256];
    __shared__ int cur[256];
    __shared__ int sorted[BCAP];
    const int b = blockIdx.x;
    const int t = threadIdx.x;
    const int n = min(gcur[b], BCAP);
    const unsigned int* rec = brec + (size_t)b * BCAP;

    hist[t] = 0;
    __syncthreads();
    for (int i = t; i < n; i += 256) atomicAdd(&hist[rec[i] >> 24], 1);
    __syncthreads();

    int c = hist[t];
    scanv[t] = c;
    __syncthreads();
    for (int off = 1; off < 256; off <<= 1) {
        int add = (t >= off) ? scanv[t - off] : 0;
        __syncthreads();
        scanv[t] += add;
        __syncthreads();
    }
    int base = scanv[t] - c;  // exclusive
    cur[t] = base;
    __syncthreads();

    for (int i = t; i < n; i += 256) {
        unsigned int r = rec[i];
        int p = atomicAdd(&cur[r >> 24], 1);
        sorted[p] = (int)(r & 0xFFFFFF);
    }
    __syncthreads();

    for (int i = t; i < n; i += 256) csr[(size_t)b * BCAP + i] = sorted[i];

    int v = b * 256 + t;
    if (v < NN) {
        st[v] = b * BCAP + base;
        en[v] = b * BCAP + base + c;
        dis[v] = rsqrtf((float)(c + 1));
    }
}

// ---------------- layer-1 transform: H' = (X @ W) * dis[row]  (f32 in, bf16 out) ----------------

__global__ __launch_bounds__(256) void gemm64_f32in_kernel(const float* __restrict__ X,
                                                           const float* __restrict__ W,
                                                           const float* __restrict__ dis,
                                                           bf16_t* __restrict__ Hout, int n) {
    __shared__ float xs[64][64];
    const int lane = threadIdx.x & 63;
    const int wid = threadIdx.x >> 6;

    float w[64];
#pragma unroll
    for (int k = 0; k < 64; ++k) w[k] = W[k * 64 + lane];

    const int row0 = blockIdx.x * 64;

#pragma unroll
    for (int i = 0; i < 16; ++i) {
        int idx = threadIdx.x + i * 256;
        int r = idx >> 6, c = idx & 63;
        int row = row0 + r;
        xs[r][c] = (row < n) ? X[(size_t)row * 64 + c] : 0.0f;
    }
    __syncthreads();

#pragma unroll 1
    for (int rr = 0; rr < 16; ++rr) {
        int r = wid * 16 + rr;
        int row = row0 + r;
        if (row < n) {
            float acc = 0.0f;
#pragma unroll
            for (int k = 0; k < 64; ++k) acc += xs[r][k] * w[k];
            Hout[(size_t)row * 64 + lane] = f2bf(acc * dis[row]);
        }
    }
}

// ---------------- layer-2 transform: H' = (relu(Z1) @ W) * dis[row]  (bf16 in/out) ----------------

__global__ __launch_bounds__(256) void gemm64_bf16in_kernel(const bf16_t* __restrict__ X,
                                                            const float* __restrict__ W,
                                                            const float* __restrict__ dis,
                                                            bf16_t* __restrict__ Hout, int n) {
    __shared__ float xs[64][64];
    const int lane = threadIdx.x & 63;
    const int wid = threadIdx.x >> 6;

    float w[64];
#pragma unroll
    for (int k = 0; k < 64; ++k) w[k] = W[k * 64 + lane];

    const int row0 = blockIdx.x * 64;
    const unsigned int* X2 = reinterpret_cast<const unsigned int*>(X + (size_t)row0 * 64);

    // 64 rows x 64 bf16 = 2048 dwords; 256 threads x 8
#pragma unroll
    for (int i = 0; i < 8; ++i) {
        int idx = threadIdx.x + i * 256;
        int r = idx >> 5, c2 = idx & 31;
        int row = row0 + r;
        unsigned int u = (row < n) ? X2[idx] : 0u;
        float lo = bf2f((bf16_t)(u & 0xFFFFu));
        float hi = bf2f((bf16_t)(u >> 16));
        xs[r][c2 * 2]     = fmaxf(lo, 0.0f);
        xs[r][c2 * 2 + 1] = fmaxf(hi, 0.0f);
    }
    __syncthreads();

#pragma unroll 1
    for (int rr = 0; rr < 16; ++rr) {
        int r = wid * 16 + rr;
        int row = row0 + r;
        if (row < n) {
            float acc = 0.0f;
#pragma unroll
            for (int k = 0; k < 64; ++k) acc += xs[r][k] * w[k];
            Hout[(size_t)row * 64 + lane] = f2bf(acc * dis[row]);
        }
    }
}

// ---------------- gather aggregation: one wave per node, 4-deep pipeline (bf16) ----------------
// Z[v] = f2bf( dis[v]*(H'[v] + sum_in H'[s]) + bias )

__global__ __launch_bounds__(256) void agg_kernel(const int* __restrict__ csr,
                                                  const int* __restrict__ st,
                                                  const int* __restrict__ en,
                                                  const float* __restrict__ dis,
                                                  const bf16_t* __restrict__ Hp,
                                                  const float* __restrict__ bias,
                                                  bf16_t* __restrict__ Z, int n) {
    const int lane = threadIdx.x & 63;
    int v = blockIdx.x * 4 + (threadIdx.x >> 6);
    if (v >= n) return;
    v = __builtin_amdgcn_readfirstlane(v);
    const int e0 = __builtin_amdgcn_readfirstlane(st[v]);
    const int e1 = __builtin_amdgcn_readfirstlane(en[v]);
    float a0 = bf2f(Hp[(size_t)v * 64 + lane]);  // self loop
    float a1 = 0.0f, a2 = 0.0f, a3 = 0.0f;
    int e = e0;
    for (; e + 4 <= e1; e += 4) {
        int s0 = csr[e];
        int s1 = csr[e + 1];
        int s2 = csr[e + 2];
        int s3 = csr[e + 3];
        a0 += bf2f(Hp[(size_t)s0 * 64 + lane]);
        a1 += bf2f(Hp[(size_t)s1 * 64 + lane]);
        a2 += bf2f(Hp[(size_t)s2 * 64 + lane]);
        a3 += bf2f(Hp[(size_t)s3 * 64 + lane]);
    }
    for (; e < e1; ++e) a1 += bf2f(Hp[(size_t)csr[e] * 64 + lane]);
    float z = ((a0 + a1) + (a2 + a3)) * dis[v] + bias[lane];
    Z[(size_t)v * 64 + lane] = f2bf(z);
}

// ---------------- decoder (bf16 Z) ----------------

__global__ __launch_bounds__(256) void decode_kernel(const int* __restrict__ pos,
                                                     const int* __restrict__ neg,
                                                     const bf16_t* __restrict__ Z,
                                                     float* __restrict__ out) {
    const int lane = threadIdx.x & 63;
    const int pair = blockIdx.x * 4 + (threadIdx.x >> 6);
    if (pair >= NPOS + NNEG) return;
    int a, b;
    if (pair < NPOS) {
        a = pos[pair];
        b = pos[NPOS + pair];
    } else {
        int p = pair - NPOS;
        a = neg[p];
        b = neg[NNEG + p];
    }
    float v = bf2f(Z[(size_t)a * 64 + lane]) * bf2f(Z[(size_t)b * 64 + lane]);
#pragma unroll
    for (int off = 32; off > 0; off >>= 1) v += __shfl_down(v, off, 64);
    if (lane == 0) out[pair] = v;
}

// ---------------- fallback (round-0 atomic path, all f32) ----------------

__global__ __launch_bounds__(256) void init_deg_kernel(float* __restrict__ deg, int n) {
    int i = blockIdx.x * 256 + threadIdx.x;
    if (i < n) deg[i] = 1.0f;
}
__global__ __launch_bounds__(256) void deg_count_kernel(const int* __restrict__ dst,
                                                        float* __restrict__ deg, int e) {
    int i = blockIdx.x * 256 + threadIdx.x;
    if (i < e) atomicAdd(&deg[dst[i]], 1.0f);
}
__global__ __launch_bounds__(256) void dis_kernel(float* __restrict__ deg, int n) {
    int i = blockIdx.x * 256 + threadIdx.x;
    if (i < n) deg[i] = rsqrtf(deg[i]);
}
template <bool RELU>
__global__ __launch_bounds__(256) void gemm64_f32out_kernel(const float* __restrict__ X,
                                                            const float* __restrict__ W,
                                                            float* __restrict__ Hout, int n) {
    __shared__ float xs[64][64];
    const int lane = threadIdx.x & 63;
    const int wid = threadIdx.x >> 6;
    float w[64];
#pragma unroll
    for (int k = 0; k < 64; ++k) w[k] = W[k * 64 + lane];
    const int row0 = blockIdx.x * 64;
#pragma unroll
    for (int i = 0; i < 16; ++i) {
        int idx = threadIdx.x + i * 256;
        int r = idx >> 6, c = idx & 63;
        int row = row0 + r;
        float v = (row < n) ? X[(size_t)row * 64 + c] : 0.0f;
        if (RELU) v = fmaxf(v, 0.0f);
        xs[r][c] = v;
    }
    __syncthreads();
#pragma unroll 1
    for (int rr = 0; rr < 16; ++rr) {
        int r = wid * 16 + rr;
        int row = row0 + r;
        if (row < n) {
            float acc = 0.0f;
#pragma unroll
            for (int k = 0; k < 64; ++k) acc += xs[r][k] * w[k];
            Hout[(size_t)row * 64 + lane] = acc;
        }
    }
}
__global__ __launch_bounds__(256) void selfloop_init_kernel(const float* __restrict__ H,
                                                            const float* __restrict__ dis,
                                                            const float* __restrict__ b,
                                                            float* __restrict__ Z, int n) {
    int i = blockIdx.x * 256 + threadIdx.x;
    if (i < n * 16) {
        int v = i >> 4, c = i & 15;
        float d = dis[v], d2 = d * d;
        float4 h4 = reinterpret_cast<const float4*>(H)[i];
        float4 b4 = reinterpret_cast<const float4*>(b)[c];
        float4 z4;
        z4.x = b4.x + h4.x * d2;
        z4.y = b4.y + h4.y * d2;
        z4.z = b4.z + h4.z * d2;
        z4.w = b4.w + h4.w * d2;
        reinterpret_cast<float4*>(Z)[i] = z4;
    }
}
__global__ __launch_bounds__(256) void edge_agg_kernel(const int* __restrict__ src,
                                                       const int* __restrict__ dst,
                                                       const float* __restrict__ dis,
                                                       const float* __restrict__ H,
                                                       float* __restrict__ Z, int e) {
    const int lane = threadIdx.x & 63;
    const int edge = blockIdx.x * 4 + (threadIdx.x >> 6);
    if (edge < e) {
        int s = src[edge];
        int d = dst[edge];
        float nm = dis[s] * dis[d];
        float v = H[(size_t)s * 64 + lane] * nm;
        atomicAdd(&Z[(size_t)d * 64 + lane], v);
    }
}
__global__ __launch_bounds__(256) void decode_f32_kernel(const int* __restrict__ pos,
                                                         const int* __restrict__ neg,
                                                         const float* __restrict__ Z,
                                                         float* __restrict__ out) {
    const int lane = threadIdx.x & 63;
    const int pair = blockIdx.x * 4 + (threadIdx.x >> 6);
    if (pair >= NPOS + NNEG) return;
    int a, b;
    if (pair < NPOS) {
        a = pos[pair];
        b = pos[NPOS + pair];
    } else {
        int p = pair - NPOS;
        a = neg[p];
        b = neg[NNEG + p];
    }
    float v = Z[(size_t)a * 64 + lane] * Z[(size_t)b * 64 + lane];
#pragma unroll
    for (int off = 32; off > 0; off >>= 1) v += __shfl_down(v, off, 64);
    if (lane == 0) out[pair] = v;
}

// ---------------- launch ----------------

extern "C" void kernel_launch(void* const* d_in, const int* in_sizes, int n_in,
                              void* d_out, int out_size, void* d_ws, size_t ws_size,
                              hipStream_t stream) {
    const float* x   = (const float*)d_in[0];
    const int*   ei  = (const int*)d_in[1];
    const int*   pos = (const int*)d_in[2];
    const int*   neg = (const int*)d_in[3];
    const float* W1  = (const float*)d_in[4];
    const float* b1  = (const float*)d_in[5];
    const float* W2  = (const float*)d_in[6];
    const float* b2  = (const float*)d_in[7];
    float* out = (float*)d_out;

    const int* src = ei;
    const int* dst = ei + NE;

    char* ws = (char*)d_ws;
    size_t o = 0;
    auto alloc = [&](size_t bytes) {
        size_t p = o;
        o = (o + bytes + 255) & ~(size_t)255;
        return p;
    };
    float*        dis  = (float*)(ws + alloc((size_t)NN * 4));
    int*          gcur = (int*)(ws + alloc((size_t)NBUCK * 4));
    unsigned int* brec = (unsigned int*)(ws + alloc((size_t)NBUCK * BCAP * 4));
    int*          csr  = (int*)(ws + alloc((size_t)NBUCK * BCAP * 4));
    int*          stA  = (int*)(ws + alloc((size_t)NN * 4));
    int*          enA  = (int*)(ws + alloc((size_t)NN * 4));
    bf16_t*       bufA = (bf16_t*)(ws + alloc((size_t)NN * 64 * 2));
    bf16_t*       bufB = (bf16_t*)(ws + alloc((size_t)NN * 64 * 2));

    if (o <= ws_size) {
        // ---- bucketed CSR gather path (bf16 intermediates) ----
        hipMemsetAsync(gcur, 0, (size_t)NBUCK * 4, stream);
        bin_kernel<<<(NE + TILE - 1) / TILE, 256, 0, stream>>>(src, dst, gcur, brec);
        bucket_csr_kernel<<<NBUCK, 256, 0, stream>>>(gcur, brec, csr, stA, enA, dis);

        gemm64_f32in_kernel<<<(NN + 63) / 64, 256, 0, stream>>>(x, W1, dis, bufA, NN);
        agg_kernel<<<(NN + 3) / 4, 256, 0, stream>>>(csr, stA, enA, dis, bufA, b1, bufB, NN);

        gemm64_bf16in_kernel<<<(NN + 63) / 64, 256, 0, stream>>>(bufB, W2, dis, bufA, NN);
        agg_kernel<<<(NN + 3) / 4, 256, 0, stream>>>(csr, stA, enA, dis, bufA, b2, bufB, NN);

        decode_kernel<<<((NPOS + NNEG) + 3) / 4, 256, 0, stream>>>(pos, neg, bufB, out);
    } else {
        // ---- fallback: atomic scatter path (f32) ----
        float* fdis = (float*)ws;
        size_t foff = ((size_t)NN * 4 + 255) / 256 * 256;
        float* fA = (float*)(ws + foff);
        float* fB = fA + (size_t)NN * 64;

        init_deg_kernel<<<(NN + 255) / 256, 256, 0, stream>>>(fdis, NN);
        deg_count_kernel<<<(NE + 255) / 256, 256, 0, stream>>>(dst, fdis, NE);
        dis_kernel<<<(NN + 255) / 256, 256, 0, stream>>>(fdis, NN);

        gemm64_f32out_kernel<false><<<(NN + 63) / 64, 256, 0, stream>>>(x, W1, fA, NN);
        selfloop_init_kernel<<<(NN * 16 + 255) / 256, 256, 0, stream>>>(fA, fdis, b1, fB, NN);
        edge_agg_kernel<<<(NE + 3) / 4, 256, 0, stream>>>(src, dst, fdis, fA, fB, NE);

        gemm64_f32out_kernel<true><<<(NN + 63) / 64, 256, 0, stream>>>(fB, W2, fA, NN);
        selfloop_init_kernel<<<(NN * 16 + 255) / 256, 256, 0, stream>>>(fA, fdis, b2, fB, NN);
        edge_agg_kernel<<<(NE + 3) / 4, 256, 0, stream>>>(src, dst, fdis, fA, fB, NE);

        decode_f32_kernel<<<((NPOS + NNEG) + 3) / 4, 256, 0, stream>>>(pos, neg, fB, out);
    }
}

// Round 6
// 189.590 us; speedup vs baseline: 6.1869x; 1.1362x over previous
//
#include <hip/hip_runtime.h>

#define NN 100000
#define NE 1200000
#define NPOS 100000
#define NNEG 100000

#define NBUCK ((NN + 255) / 256)    // 391 buckets of 256 nodes
#define BCAP 3712                   // mean 3070, sd ~55 -> 11.7 sigma margin
#define TILE 4096
#define EPT 16                      // edges per thread in bin_kernel

typedef unsigned short bf16_t;

__device__ __forceinline__ float bf2f(bf16_t b) {
    return __uint_as_float(((unsigned int)b) << 16);
}
__device__ __forceinline__ bf16_t f2bf(float f) {
    unsigned int u = __float_as_uint(f);
    u += 0x7FFFu + ((u >> 16) & 1u);  // round-to-nearest-even
    return (bf16_t)(u >> 16);
}
__device__ __forceinline__ float ulo(unsigned int u) { return bf2f((bf16_t)(u & 0xFFFFu)); }
__device__ __forceinline__ float uhi(unsigned int u) { return bf2f((bf16_t)(u >> 16)); }

// ---------------- stage 1: bin edges by dst bucket (dst>>8) ----------------

__global__ __launch_bounds__(256) void bin_kernel(const int* __restrict__ src,
                                                  const int* __restrict__ dst,
                                                  int* __restrict__ gcur,
                                                  unsigned int* __restrict__ brec) {
    __shared__ int hcnt[NBUCK];
    __shared__ int hbase[NBUCK];
    for (int b = threadIdx.x; b < NBUCK; b += 256) hcnt[b] = 0;
    __syncthreads();

    const int tile0 = blockIdx.x * TILE;
    int bk[EPT];
    int rank[EPT];
    unsigned int rec[EPT];
#pragma unroll
    for (int i = 0; i < EPT; ++i) {
        int e = tile0 + i * 256 + threadIdx.x;
        if (e < NE) {
            int s = src[e];
            int d = dst[e];
            bk[i] = d >> 8;
            rec[i] = ((unsigned int)(d & 255) << 24) | (unsigned int)s;
            rank[i] = atomicAdd(&hcnt[bk[i]], 1);
        } else {
            bk[i] = -1;
        }
    }
    __syncthreads();
    for (int b = threadIdx.x; b < NBUCK; b += 256) {
        int h = hcnt[b];
        if (h > 0) hbase[b] = atomicAdd(&gcur[b], h);
    }
    __syncthreads();
#pragma unroll
    for (int i = 0; i < EPT; ++i) {
        if (bk[i] >= 0) {
            int p = hbase[bk[i]] + rank[i];
            if (p < BCAP) brec[(size_t)bk[i] * BCAP + p] = rec[i];
        }
    }
}

// ---------------- stage 2: per-bucket sort by dstLocal -> CSR slice ----------------

__global__ __launch_bounds__(256) void bucket_csr_kernel(const int* __restrict__ gcur,
                                                         const unsigned int* __restrict__ brec,
                                                         int* __restrict__ csr,
                                                         int* __restrict__ st,
                                                         int* __restrict__ en,
                                                         float* __restrict__ dis) {
    __shared__ int hist[256];
    __shared__ int scanv[256];
    __shared__ int cur[256];
    __shared__ int sorted[BCAP];
    const int b = blockIdx.x;
    const int t = threadIdx.x;
    const int n = min(gcur[b], BCAP);
    const unsigned int* rec = brec + (size_t)b * BCAP;

    hist[t] = 0;
    __syncthreads();
    for (int i = t; i < n; i += 256) atomicAdd(&hist[rec[i] >> 24], 1);
    __syncthreads();

    int c = hist[t];
    scanv[t] = c;
    __syncthreads();
    for (int off = 1; off < 256; off <<= 1) {
        int add = (t >= off) ? scanv[t - off] : 0;
        __syncthreads();
        scanv[t] += add;
        __syncthreads();
    }
    int base = scanv[t] - c;  // exclusive
    cur[t] = base;
    __syncthreads();

    for (int i = t; i < n; i += 256) {
        unsigned int r = rec[i];
        int p = atomicAdd(&cur[r >> 24], 1);
        sorted[p] = (int)(r & 0xFFFFFF);
    }
    __syncthreads();

    for (int i = t; i < n; i += 256) csr[(size_t)b * BCAP + i] = sorted[i];

    int v = b * 256 + t;
    if (v < NN) {
        st[v] = b * BCAP + base;
        en[v] = b * BCAP + base + c;
        dis[v] = rsqrtf((float)(c + 1));
    }
}

// ---------------- layer-1 transform: H' = (X @ W) * dis[row]  (f32 in, bf16 out) ----------------

__global__ __launch_bounds__(256) void gemm64_f32in_kernel(const float* __restrict__ X,
                                                           const float* __restrict__ W,
                                                           const float* __restrict__ dis,
                                                           bf16_t* __restrict__ Hout, int n) {
    __shared__ float xs[64][64];
    const int lane = threadIdx.x & 63;
    const int wid = threadIdx.x >> 6;

    float w[64];
#pragma unroll
    for (int k = 0; k < 64; ++k) w[k] = W[k * 64 + lane];

    const int row0 = blockIdx.x * 64;

#pragma unroll
    for (int i = 0; i < 16; ++i) {
        int idx = threadIdx.x + i * 256;
        int r = idx >> 6, c = idx & 63;
        int row = row0 + r;
        xs[r][c] = (row < n) ? X[(size_t)row * 64 + c] : 0.0f;
    }
    __syncthreads();

#pragma unroll 1
    for (int rr = 0; rr < 16; ++rr) {
        int r = wid * 16 + rr;
        int row = row0 + r;
        if (row < n) {
            float acc = 0.0f;
#pragma unroll
            for (int k = 0; k < 64; ++k) acc += xs[r][k] * w[k];
            Hout[(size_t)row * 64 + lane] = f2bf(acc * dis[row]);
        }
    }
}

// ---------------- layer-2 transform: H' = (relu(Z1) @ W) * dis[row]  (bf16 in/out) ----------------

__global__ __launch_bounds__(256) void gemm64_bf16in_kernel(const bf16_t* __restrict__ X,
                                                            const float* __restrict__ W,
                                                            const float* __restrict__ dis,
                                                            bf16_t* __restrict__ Hout, int n) {
    __shared__ float xs[64][64];
    const int lane = threadIdx.x & 63;
    const int wid = threadIdx.x >> 6;

    float w[64];
#pragma unroll
    for (int k = 0; k < 64; ++k) w[k] = W[k * 64 + lane];

    const int row0 = blockIdx.x * 64;
    const unsigned int* X2 = reinterpret_cast<const unsigned int*>(X + (size_t)row0 * 64);

#pragma unroll
    for (int i = 0; i < 8; ++i) {
        int idx = threadIdx.x + i * 256;
        int r = idx >> 5, c2 = idx & 31;
        int row = row0 + r;
        unsigned int u = (row < n) ? X2[idx] : 0u;
        xs[r][c2 * 2]     = fmaxf(ulo(u), 0.0f);
        xs[r][c2 * 2 + 1] = fmaxf(uhi(u), 0.0f);
    }
    __syncthreads();

#pragma unroll 1
    for (int rr = 0; rr < 16; ++rr) {
        int r = wid * 16 + rr;
        int row = row0 + r;
        if (row < n) {
            float acc = 0.0f;
#pragma unroll
            for (int k = 0; k < 64; ++k) acc += xs[r][k] * w[k];
            Hout[(size_t)row * 64 + lane] = f2bf(acc * dis[row]);
        }
    }
}

// ---------------- gather aggregation: half-wave per node, dword lanes ----------------
// lane owns features (2*fl, 2*fl+1); 4-deep pipeline -> 8 rows in flight per wave.
// Z[v] = f2bf( dis[v]*(H'[v] + sum_in H'[s]) + bias )

__global__ __launch_bounds__(256) void agg_kernel(const int* __restrict__ csr,
                                                  const int* __restrict__ st,
                                                  const int* __restrict__ en,
                                                  const float* __restrict__ dis,
                                                  const unsigned int* __restrict__ Hp2,
                                                  const float* __restrict__ bias,
                                                  unsigned int* __restrict__ Z2, int n) {
    const int lane = threadIdx.x & 63;
    const int half = lane >> 5;
    const int fl = lane & 31;
    int v = blockIdx.x * 8 + ((threadIdx.x >> 6) << 1) + half;
    const bool act = v < n;
    if (!act) v = n - 1;

    int e = st[v];
    const int e1 = en[v];

    // self loop seeds chain 0
    unsigned int us = Hp2[(size_t)v * 32 + fl];
    float ax0 = ulo(us), ay0 = uhi(us);
    float ax1 = 0.f, ay1 = 0.f, ax2 = 0.f, ay2 = 0.f, ax3 = 0.f, ay3 = 0.f;

    for (; e + 4 <= e1; e += 4) {
        int s0 = csr[e];
        int s1 = csr[e + 1];
        int s2 = csr[e + 2];
        int s3 = csr[e + 3];
        unsigned int u0 = Hp2[(size_t)s0 * 32 + fl];
        unsigned int u1 = Hp2[(size_t)s1 * 32 + fl];
        unsigned int u2 = Hp2[(size_t)s2 * 32 + fl];
        unsigned int u3 = Hp2[(size_t)s3 * 32 + fl];
        ax0 += ulo(u0); ay0 += uhi(u0);
        ax1 += ulo(u1); ay1 += uhi(u1);
        ax2 += ulo(u2); ay2 += uhi(u2);
        ax3 += ulo(u3); ay3 += uhi(u3);
    }
    for (; e < e1; ++e) {
        int s = csr[e];
        unsigned int u = Hp2[(size_t)s * 32 + fl];
        ax1 += ulo(u); ay1 += uhi(u);
    }

    float d = dis[v];
    float2 b2 = reinterpret_cast<const float2*>(bias)[fl];
    float zx = ((ax0 + ax1) + (ax2 + ax3)) * d + b2.x;
    float zy = ((ay0 + ay1) + (ay2 + ay3)) * d + b2.y;
    if (act) Z2[(size_t)v * 32 + fl] = ((unsigned int)f2bf(zy) << 16) | (unsigned int)f2bf(zx);
}

// ---------------- decoder: half-wave per pair, dword lanes ----------------

__global__ __launch_bounds__(256) void decode_kernel(const int* __restrict__ pos,
                                                     const int* __restrict__ neg,
                                                     const unsigned int* __restrict__ Z2,
                                                     float* __restrict__ out) {
    const int lane = threadIdx.x & 63;
    const int fl = lane & 31;
    const int pair = blockIdx.x * 8 + ((threadIdx.x >> 6) << 1) + (lane >> 5);
    if (pair >= NPOS + NNEG) return;
    int a, b;
    if (pair < NPOS) {
        a = pos[pair];
        b = pos[NPOS + pair];
    } else {
        int p = pair - NPOS;
        a = neg[p];
        b = neg[NNEG + p];
    }
    unsigned int ua = Z2[(size_t)a * 32 + fl];
    unsigned int ub = Z2[(size_t)b * 32 + fl];
    float v = ulo(ua) * ulo(ub) + uhi(ua) * uhi(ub);
#pragma unroll
    for (int off = 16; off > 0; off >>= 1) v += __shfl_xor(v, off, 64);
    if (fl == 0) out[pair] = v;
}

// ---------------- fallback (round-0 atomic path, all f32) ----------------

__global__ __launch_bounds__(256) void init_deg_kernel(float* __restrict__ deg, int n) {
    int i = blockIdx.x * 256 + threadIdx.x;
    if (i < n) deg[i] = 1.0f;
}
__global__ __launch_bounds__(256) void deg_count_kernel(const int* __restrict__ dst,
                                                        float* __restrict__ deg, int e) {
    int i = blockIdx.x * 256 + threadIdx.x;
    if (i < e) atomicAdd(&deg[dst[i]], 1.0f);
}
__global__ __launch_bounds__(256) void dis_kernel(float* __restrict__ deg, int n) {
    int i = blockIdx.x * 256 + threadIdx.x;
    if (i < n) deg[i] = rsqrtf(deg[i]);
}
template <bool RELU>
__global__ __launch_bounds__(256) void gemm64_f32out_kernel(const float* __restrict__ X,
                                                            const float* __restrict__ W,
                                                            float* __restrict__ Hout, int n) {
    __shared__ float xs[64][64];
    const int lane = threadIdx.x & 63;
    const int wid = threadIdx.x >> 6;
    float w[64];
#pragma unroll
    for (int k = 0; k < 64; ++k) w[k] = W[k * 64 + lane];
    const int row0 = blockIdx.x * 64;
#pragma unroll
    for (int i = 0; i < 16; ++i) {
        int idx = threadIdx.x + i * 256;
        int r = idx >> 6, c = idx & 63;
        int row = row0 + r;
        float v = (row < n) ? X[(size_t)row * 64 + c] : 0.0f;
        if (RELU) v = fmaxf(v, 0.0f);
        xs[r][c] = v;
    }
    __syncthreads();
#pragma unroll 1
    for (int rr = 0; rr < 16; ++rr) {
        int r = wid * 16 + rr;
        int row = row0 + r;
        if (row < n) {
            float acc = 0.0f;
#pragma unroll
            for (int k = 0; k < 64; ++k) acc += xs[r][k] * w[k];
            Hout[(size_t)row * 64 + lane] = acc;
        }
    }
}
__global__ __launch_bounds__(256) void selfloop_init_kernel(const float* __restrict__ H,
                                                            const float* __restrict__ dis,
                                                            const float* __restrict__ b,
                                                            float* __restrict__ Z, int n) {
    int i = blockIdx.x * 256 + threadIdx.x;
    if (i < n * 16) {
        int v = i >> 4, c = i & 15;
        float d = dis[v], d2 = d * d;
        float4 h4 = reinterpret_cast<const float4*>(H)[i];
        float4 b4 = reinterpret_cast<const float4*>(b)[c];
        float4 z4;
        z4.x = b4.x + h4.x * d2;
        z4.y = b4.y + h4.y * d2;
        z4.z = b4.z + h4.z * d2;
        z4.w = b4.w + h4.w * d2;
        reinterpret_cast<float4*>(Z)[i] = z4;
    }
}
__global__ __launch_bounds__(256) void edge_agg_kernel(const int* __restrict__ src,
                                                       const int* __restrict__ dst,
                                                       const float* __restrict__ dis,
                                                       const float* __restrict__ H,
                                                       float* __restrict__ Z, int e) {
    const int lane = threadIdx.x & 63;
    const int edge = blockIdx.x * 4 + (threadIdx.x >> 6);
    if (edge < e) {
        int s = src[edge];
        int d = dst[edge];
        float nm = dis[s] * dis[d];
        float v = H[(size_t)s * 64 + lane] * nm;
        atomicAdd(&Z[(size_t)d * 64 + lane], v);
    }
}
__global__ __launch_bounds__(256) void decode_f32_kernel(const int* __restrict__ pos,
                                                         const int* __restrict__ neg,
                                                         const float* __restrict__ Z,
                                                         float* __restrict__ out) {
    const int lane = threadIdx.x & 63;
    const int pair = blockIdx.x * 4 + (threadIdx.x >> 6);
    if (pair >= NPOS + NNEG) return;
    int a, b;
    if (pair < NPOS) {
        a = pos[pair];
        b = pos[NPOS + pair];
    } else {
        int p = pair - NPOS;
        a = neg[p];
        b = neg[NNEG + p];
    }
    float v = Z[(size_t)a * 64 + lane] * Z[(size_t)b * 64 + lane];
#pragma unroll
    for (int off = 32; off > 0; off >>= 1) v += __shfl_down(v, off, 64);
    if (lane == 0) out[pair] = v;
}

// ---------------- launch ----------------

extern "C" void kernel_launch(void* const* d_in, const int* in_sizes, int n_in,
                              void* d_out, int out_size, void* d_ws, size_t ws_size,
                              hipStream_t stream) {
    const float* x   = (const float*)d_in[0];
    const int*   ei  = (const int*)d_in[1];
    const int*   pos = (const int*)d_in[2];
    const int*   neg = (const int*)d_in[3];
    const float* W1  = (const float*)d_in[4];
    const float* b1  = (const float*)d_in[5];
    const float* W2  = (const float*)d_in[6];
    const float* b2  = (const float*)d_in[7];
    float* out = (float*)d_out;

    const int* src = ei;
    const int* dst = ei + NE;

    char* ws = (char*)d_ws;
    size_t o = 0;
    auto alloc = [&](size_t bytes) {
        size_t p = o;
        o = (o + bytes + 255) & ~(size_t)255;
        return p;
    };
    float*        dis  = (float*)(ws + alloc((size_t)NN * 4));
    int*          gcur = (int*)(ws + alloc((size_t)NBUCK * 4));
    unsigned int* brec = (unsigned int*)(ws + alloc((size_t)NBUCK * BCAP * 4));
    int*          csr  = (int*)(ws + alloc((size_t)NBUCK * BCAP * 4));
    int*          stA  = (int*)(ws + alloc((size_t)NN * 4));
    int*          enA  = (int*)(ws + alloc((size_t)NN * 4));
    bf16_t*       bufA = (bf16_t*)(ws + alloc((size_t)NN * 64 * 2));
    bf16_t*       bufB = (bf16_t*)(ws + alloc((size_t)NN * 64 * 2));

    if (o <= ws_size) {
        // ---- bucketed CSR gather path (bf16 intermediates, dword-lane agg) ----
        hipMemsetAsync(gcur, 0, (size_t)NBUCK * 4, stream);
        bin_kernel<<<(NE + TILE - 1) / TILE, 256, 0, stream>>>(src, dst, gcur, brec);
        bucket_csr_kernel<<<NBUCK, 256, 0, stream>>>(gcur, brec, csr, stA, enA, dis);

        gemm64_f32in_kernel<<<(NN + 63) / 64, 256, 0, stream>>>(x, W1, dis, bufA, NN);
        agg_kernel<<<(NN + 7) / 8, 256, 0, stream>>>(csr, stA, enA, dis,
                                                     (const unsigned int*)bufA, b1,
                                                     (unsigned int*)bufB, NN);

        gemm64_bf16in_kernel<<<(NN + 63) / 64, 256, 0, stream>>>(bufB, W2, dis, bufA, NN);
        agg_kernel<<<(NN + 7) / 8, 256, 0, stream>>>(csr, stA, enA, dis,
                                                     (const unsigned int*)bufA, b2,
                                                     (unsigned int*)bufB, NN);

        decode_kernel<<<((NPOS + NNEG) + 7) / 8, 256, 0, stream>>>(pos, neg,
                                                                   (const unsigned int*)bufB, out);
    } else {
        // ---- fallback: atomic scatter path (f32) ----
        float* fdis = (float*)ws;
        size_t foff = ((size_t)NN * 4 + 255) / 256 * 256;
        float* fA = (float*)(ws + foff);
        float* fB = fA + (size_t)NN * 64;

        init_deg_kernel<<<(NN + 255) / 256, 256, 0, stream>>>(fdis, NN);
        deg_count_kernel<<<(NE + 255) / 256, 256, 0, stream>>>(dst, fdis, NE);
        dis_kernel<<<(NN + 255) / 256, 256, 0, stream>>>(fdis, NN);

        gemm64_f32out_kernel<false><<<(NN + 63) / 64, 256, 0, stream>>>(x, W1, fA, NN);
        selfloop_init_kernel<<<(NN * 16 + 255) / 256, 256, 0, stream>>>(fA, fdis, b1, fB, NN);
        edge_agg_kernel<<<(NE + 3) / 4, 256, 0, stream>>>(src, dst, fdis, fA, fB, NE);

        gemm64_f32out_kernel<true><<<(NN + 63) / 64, 256, 0, stream>>>(fB, W2, fA, NN);
        selfloop_init_kernel<<<(NN * 16 + 255) / 256, 256, 0, stream>>>(fA, fdis, b2, fB, NN);
        edge_agg_kernel<<<(NE + 3) / 4, 256, 0, stream>>>(src, dst, fdis, fA, fB, NE);

        decode_f32_kernel<<<((NPOS + NNEG) + 3) / 4, 256, 0, stream>>>(pos, neg, fB, out);
    }
}

// Round 7
// 186.952 us; speedup vs baseline: 6.2743x; 1.0141x over previous
//
#include <hip/hip_runtime.h>

#define NN 100000
#define NE 1200000
#define NPOS 100000
#define NNEG 100000

#define NBUCK ((NN + 255) / 256)    // 391 buckets of 256 nodes
#define BCAP 3712                   // mean 3070, sd ~55 -> 11.7 sigma margin
#define TILE 4096
#define EPT 16                      // edges per thread in bin_kernel

typedef unsigned short bf16_t;

__device__ __forceinline__ float bf2f(bf16_t b) {
    return __uint_as_float(((unsigned int)b) << 16);
}
__device__ __forceinline__ bf16_t f2bf(float f) {
    unsigned int u = __float_as_uint(f);
    u += 0x7FFFu + ((u >> 16) & 1u);  // round-to-nearest-even
    return (bf16_t)(u >> 16);
}
__device__ __forceinline__ float ulo(unsigned int u) { return bf2f((bf16_t)(u & 0xFFFFu)); }
__device__ __forceinline__ float uhi(unsigned int u) { return bf2f((bf16_t)(u >> 16)); }

// ---------------- tiny zero kernel (replaces hipMemsetAsync) ----------------

__global__ __launch_bounds__(256) void zero_gcur_kernel(int* __restrict__ gcur) {
    int i = blockIdx.x * 256 + threadIdx.x;
    if (i < NBUCK) gcur[i] = 0;
}

// ---------------- stage 1: bin edges by dst bucket (dst>>8) ----------------

__global__ __launch_bounds__(256) void bin_kernel(const int* __restrict__ src,
                                                  const int* __restrict__ dst,
                                                  int* __restrict__ gcur,
                                                  unsigned int* __restrict__ brec) {
    __shared__ int hcnt[NBUCK];
    __shared__ int hbase[NBUCK];
    for (int b = threadIdx.x; b < NBUCK; b += 256) hcnt[b] = 0;
    __syncthreads();

    const int tile0 = blockIdx.x * TILE;
    int bk[EPT];
    int rank[EPT];
    unsigned int rec[EPT];
#pragma unroll
    for (int i = 0; i < EPT; ++i) {
        int e = tile0 + i * 256 + threadIdx.x;
        if (e < NE) {
            int s = src[e];
            int d = dst[e];
            bk[i] = d >> 8;
            rec[i] = ((unsigned int)(d & 255) << 24) | (unsigned int)s;
            rank[i] = atomicAdd(&hcnt[bk[i]], 1);
        } else {
            bk[i] = -1;
        }
    }
    __syncthreads();
    for (int b = threadIdx.x; b < NBUCK; b += 256) {
        int h = hcnt[b];
        if (h > 0) hbase[b] = atomicAdd(&gcur[b], h);
    }
    __syncthreads();
#pragma unroll
    for (int i = 0; i < EPT; ++i) {
        if (bk[i] >= 0) {
            int p = hbase[bk[i]] + rank[i];
            if (p < BCAP) brec[(size_t)bk[i] * BCAP + p] = rec[i];
        }
    }
}

// ---------------- stage 2: per-bucket sort by dstLocal -> CSR slice ----------------

__global__ __launch_bounds__(256) void bucket_csr_kernel(const int* __restrict__ gcur,
                                                         const unsigned int* __restrict__ brec,
                                                         int* __restrict__ csr,
                                                         int* __restrict__ st,
                                                         int* __restrict__ en,
                                                         float* __restrict__ dis) {
    __shared__ int hist[256];
    __shared__ int scanv[256];
    __shared__ int cur[256];
    __shared__ int sorted[BCAP];
    const int b = blockIdx.x;
    const int t = threadIdx.x;
    const int n = min(gcur[b], BCAP);
    const unsigned int* rec = brec + (size_t)b * BCAP;

    hist[t] = 0;
    __syncthreads();
    for (int i = t; i < n; i += 256) atomicAdd(&hist[rec[i] >> 24], 1);
    __syncthreads();

    int c = hist[t];
    scanv[t] = c;
    __syncthreads();
    for (int off = 1; off < 256; off <<= 1) {
        int add = (t >= off) ? scanv[t - off] : 0;
        __syncthreads();
        scanv[t] += add;
        __syncthreads();
    }
    int base = scanv[t] - c;  // exclusive
    cur[t] = base;
    __syncthreads();

    for (int i = t; i < n; i += 256) {
        unsigned int r = rec[i];
        int p = atomicAdd(&cur[r >> 24], 1);
        sorted[p] = (int)(r & 0xFFFFFF);
    }
    __syncthreads();

    for (int i = t; i < n; i += 256) csr[(size_t)b * BCAP + i] = sorted[i];

    int v = b * 256 + t;
    if (v < NN) {
        st[v] = b * BCAP + base;
        en[v] = b * BCAP + base + c;
        dis[v] = rsqrtf((float)(c + 1));
    }
}

// ---------------- layer-1 transform: H' = (X @ W) * dis[row]  (f32 in, bf16 out) ----------------
// 4 independent accumulators break the strict-FP dependent FMA chain (ILP 4).

__global__ __launch_bounds__(256) void gemm64_f32in_kernel(const float* __restrict__ X,
                                                           const float* __restrict__ W,
                                                           const float* __restrict__ dis,
                                                           bf16_t* __restrict__ Hout, int n) {
    __shared__ float xs[64][64];
    const int lane = threadIdx.x & 63;
    const int wid = threadIdx.x >> 6;

    float w[64];
#pragma unroll
    for (int k = 0; k < 64; ++k) w[k] = W[k * 64 + lane];

    const int row0 = blockIdx.x * 64;

#pragma unroll
    for (int i = 0; i < 16; ++i) {
        int idx = threadIdx.x + i * 256;
        int r = idx >> 6, c = idx & 63;
        int row = row0 + r;
        xs[r][c] = (row < n) ? X[(size_t)row * 64 + c] : 0.0f;
    }
    __syncthreads();

#pragma unroll 1
    for (int rr = 0; rr < 16; ++rr) {
        int r = wid * 16 + rr;
        int row = row0 + r;
        if (row < n) {
            float a0 = 0.f, a1 = 0.f, a2 = 0.f, a3 = 0.f;
#pragma unroll
            for (int k = 0; k < 64; k += 4) {
                a0 += xs[r][k]     * w[k];
                a1 += xs[r][k + 1] * w[k + 1];
                a2 += xs[r][k + 2] * w[k + 2];
                a3 += xs[r][k + 3] * w[k + 3];
            }
            float acc = (a0 + a1) + (a2 + a3);
            Hout[(size_t)row * 64 + lane] = f2bf(acc * dis[row]);
        }
    }
}

// ---------------- layer-2 transform: H' = (relu(Z1) @ W) * dis[row]  (bf16 in/out) ----------------

__global__ __launch_bounds__(256) void gemm64_bf16in_kernel(const bf16_t* __restrict__ X,
                                                            const float* __restrict__ W,
                                                            const float* __restrict__ dis,
                                                            bf16_t* __restrict__ Hout, int n) {
    __shared__ float xs[64][64];
    const int lane = threadIdx.x & 63;
    const int wid = threadIdx.x >> 6;

    float w[64];
#pragma unroll
    for (int k = 0; k < 64; ++k) w[k] = W[k * 64 + lane];

    const int row0 = blockIdx.x * 64;
    const unsigned int* X2 = reinterpret_cast<const unsigned int*>(X + (size_t)row0 * 64);

#pragma unroll
    for (int i = 0; i < 8; ++i) {
        int idx = threadIdx.x + i * 256;
        int r = idx >> 5, c2 = idx & 31;
        int row = row0 + r;
        unsigned int u = (row < n) ? X2[idx] : 0u;
        xs[r][c2 * 2]     = fmaxf(ulo(u), 0.0f);
        xs[r][c2 * 2 + 1] = fmaxf(uhi(u), 0.0f);
    }
    __syncthreads();

#pragma unroll 1
    for (int rr = 0; rr < 16; ++rr) {
        int r = wid * 16 + rr;
        int row = row0 + r;
        if (row < n) {
            float a0 = 0.f, a1 = 0.f, a2 = 0.f, a3 = 0.f;
#pragma unroll
            for (int k = 0; k < 64; k += 4) {
                a0 += xs[r][k]     * w[k];
                a1 += xs[r][k + 1] * w[k + 1];
                a2 += xs[r][k + 2] * w[k + 2];
                a3 += xs[r][k + 3] * w[k + 3];
            }
            float acc = (a0 + a1) + (a2 + a3);
            Hout[(size_t)row * 64 + lane] = f2bf(acc * dis[row]);
        }
    }
}

// ---------------- gather aggregation: half-wave per node, dword lanes ----------------

__global__ __launch_bounds__(256) void agg_kernel(const int* __restrict__ csr,
                                                  const int* __restrict__ st,
                                                  const int* __restrict__ en,
                                                  const float* __restrict__ dis,
                                                  const unsigned int* __restrict__ Hp2,
                                                  const float* __restrict__ bias,
                                                  unsigned int* __restrict__ Z2, int n) {
    const int lane = threadIdx.x & 63;
    const int half = lane >> 5;
    const int fl = lane & 31;
    int v = blockIdx.x * 8 + ((threadIdx.x >> 6) << 1) + half;
    const bool act = v < n;
    if (!act) v = n - 1;

    int e = st[v];
    const int e1 = en[v];

    unsigned int us = Hp2[(size_t)v * 32 + fl];
    float ax0 = ulo(us), ay0 = uhi(us);
    float ax1 = 0.f, ay1 = 0.f, ax2 = 0.f, ay2 = 0.f, ax3 = 0.f, ay3 = 0.f;

    for (; e + 4 <= e1; e += 4) {
        int s0 = csr[e];
        int s1 = csr[e + 1];
        int s2 = csr[e + 2];
        int s3 = csr[e + 3];
        unsigned int u0 = Hp2[(size_t)s0 * 32 + fl];
        unsigned int u1 = Hp2[(size_t)s1 * 32 + fl];
        unsigned int u2 = Hp2[(size_t)s2 * 32 + fl];
        unsigned int u3 = Hp2[(size_t)s3 * 32 + fl];
        ax0 += ulo(u0); ay0 += uhi(u0);
        ax1 += ulo(u1); ay1 += uhi(u1);
        ax2 += ulo(u2); ay2 += uhi(u2);
        ax3 += ulo(u3); ay3 += uhi(u3);
    }
    for (; e < e1; ++e) {
        int s = csr[e];
        unsigned int u = Hp2[(size_t)s * 32 + fl];
        ax1 += ulo(u); ay1 += uhi(u);
    }

    float d = dis[v];
    float2 b2 = reinterpret_cast<const float2*>(bias)[fl];
    float zx = ((ax0 + ax1) + (ax2 + ax3)) * d + b2.x;
    float zy = ((ay0 + ay1) + (ay2 + ay3)) * d + b2.y;
    if (act) Z2[(size_t)v * 32 + fl] = ((unsigned int)f2bf(zy) << 16) | (unsigned int)f2bf(zx);
}

// ---------------- decoder: half-wave per pair, dword lanes ----------------

__global__ __launch_bounds__(256) void decode_kernel(const int* __restrict__ pos,
                                                     const int* __restrict__ neg,
                                                     const unsigned int* __restrict__ Z2,
                                                     float* __restrict__ out) {
    const int lane = threadIdx.x & 63;
    const int fl = lane & 31;
    const int pair = blockIdx.x * 8 + ((threadIdx.x >> 6) << 1) + (lane >> 5);
    if (pair >= NPOS + NNEG) return;
    int a, b;
    if (pair < NPOS) {
        a = pos[pair];
        b = pos[NPOS + pair];
    } else {
        int p = pair - NPOS;
        a = neg[p];
        b = neg[NNEG + p];
    }
    unsigned int ua = Z2[(size_t)a * 32 + fl];
    unsigned int ub = Z2[(size_t)b * 32 + fl];
    float v = ulo(ua) * ulo(ub) + uhi(ua) * uhi(ub);
#pragma unroll
    for (int off = 16; off > 0; off >>= 1) v += __shfl_xor(v, off, 64);
    if (fl == 0) out[pair] = v;
}

// ---------------- fallback (round-0 atomic path, all f32) ----------------

__global__ __launch_bounds__(256) void init_deg_kernel(float* __restrict__ deg, int n) {
    int i = blockIdx.x * 256 + threadIdx.x;
    if (i < n) deg[i] = 1.0f;
}
__global__ __launch_bounds__(256) void deg_count_kernel(const int* __restrict__ dst,
                                                        float* __restrict__ deg, int e) {
    int i = blockIdx.x * 256 + threadIdx.x;
    if (i < e) atomicAdd(&deg[dst[i]], 1.0f);
}
__global__ __launch_bounds__(256) void dis_kernel(float* __restrict__ deg, int n) {
    int i = blockIdx.x * 256 + threadIdx.x;
    if (i < n) deg[i] = rsqrtf(deg[i]);
}
template <bool RELU>
__global__ __launch_bounds__(256) void gemm64_f32out_kernel(const float* __restrict__ X,
                                                            const float* __restrict__ W,
                                                            float* __restrict__ Hout, int n) {
    __shared__ float xs[64][64];
    const int lane = threadIdx.x & 63;
    const int wid = threadIdx.x >> 6;
    float w[64];
#pragma unroll
    for (int k = 0; k < 64; ++k) w[k] = W[k * 64 + lane];
    const int row0 = blockIdx.x * 64;
#pragma unroll
    for (int i = 0; i < 16; ++i) {
        int idx = threadIdx.x + i * 256;
        int r = idx >> 6, c = idx & 63;
        int row = row0 + r;
        float v = (row < n) ? X[(size_t)row * 64 + c] : 0.0f;
        if (RELU) v = fmaxf(v, 0.0f);
        xs[r][c] = v;
    }
    __syncthreads();
#pragma unroll 1
    for (int rr = 0; rr < 16; ++rr) {
        int r = wid * 16 + rr;
        int row = row0 + r;
        if (row < n) {
            float acc = 0.0f;
#pragma unroll
            for (int k = 0; k < 64; ++k) acc += xs[r][k] * w[k];
            Hout[(size_t)row * 64 + lane] = acc;
        }
    }
}
__global__ __launch_bounds__(256) void selfloop_init_kernel(const float* __restrict__ H,
                                                            const float* __restrict__ dis,
                                                            const float* __restrict__ b,
                                                            float* __restrict__ Z, int n) {
    int i = blockIdx.x * 256 + threadIdx.x;
    if (i < n * 16) {
        int v = i >> 4, c = i & 15;
        float d = dis[v], d2 = d * d;
        float4 h4 = reinterpret_cast<const float4*>(H)[i];
        float4 b4 = reinterpret_cast<const float4*>(b)[c];
        float4 z4;
        z4.x = b4.x + h4.x * d2;
        z4.y = b4.y + h4.y * d2;
        z4.z = b4.z + h4.z * d2;
        z4.w = b4.w + h4.w * d2;
        reinterpret_cast<float4*>(Z)[i] = z4;
    }
}
__global__ __launch_bounds__(256) void edge_agg_kernel(const int* __restrict__ src,
                                                       const int* __restrict__ dst,
                                                       const float* __restrict__ dis,
                                                       const float* __restrict__ H,
                                                       float* __restrict__ Z, int e) {
    const int lane = threadIdx.x & 63;
    const int edge = blockIdx.x * 4 + (threadIdx.x >> 6);
    if (edge < e) {
        int s = src[edge];
        int d = dst[edge];
        float nm = dis[s] * dis[d];
        float v = H[(size_t)s * 64 + lane] * nm;
        atomicAdd(&Z[(size_t)d * 64 + lane], v);
    }
}
__global__ __launch_bounds__(256) void decode_f32_kernel(const int* __restrict__ pos,
                                                         const int* __restrict__ neg,
                                                         const float* __restrict__ Z,
                                                         float* __restrict__ out) {
    const int lane = threadIdx.x & 63;
    const int pair = blockIdx.x * 4 + (threadIdx.x >> 6);
    if (pair >= NPOS + NNEG) return;
    int a, b;
    if (pair < NPOS) {
        a = pos[pair];
        b = pos[NPOS + pair];
    } else {
        int p = pair - NPOS;
        a = neg[p];
        b = neg[NNEG + p];
    }
    float v = Z[(size_t)a * 64 + lane] * Z[(size_t)b * 64 + lane];
#pragma unroll
    for (int off = 32; off > 0; off >>= 1) v += __shfl_down(v, off, 64);
    if (lane == 0) out[pair] = v;
}

// ---------------- launch ----------------

extern "C" void kernel_launch(void* const* d_in, const int* in_sizes, int n_in,
                              void* d_out, int out_size, void* d_ws, size_t ws_size,
                              hipStream_t stream) {
    const float* x   = (const float*)d_in[0];
    const int*   ei  = (const int*)d_in[1];
    const int*   pos = (const int*)d_in[2];
    const int*   neg = (const int*)d_in[3];
    const float* W1  = (const float*)d_in[4];
    const float* b1  = (const float*)d_in[5];
    const float* W2  = (const float*)d_in[6];
    const float* b2  = (const float*)d_in[7];
    float* out = (float*)d_out;

    const int* src = ei;
    const int* dst = ei + NE;

    char* ws = (char*)d_ws;
    size_t o = 0;
    auto alloc = [&](size_t bytes) {
        size_t p = o;
        o = (o + bytes + 255) & ~(size_t)255;
        return p;
    };
    float*        dis  = (float*)(ws + alloc((size_t)NN * 4));
    int*          gcur = (int*)(ws + alloc((size_t)NBUCK * 4));
    unsigned int* brec = (unsigned int*)(ws + alloc((size_t)NBUCK * BCAP * 4));
    int*          csr  = (int*)(ws + alloc((size_t)NBUCK * BCAP * 4));
    int*          stA  = (int*)(ws + alloc((size_t)NN * 4));
    int*          enA  = (int*)(ws + alloc((size_t)NN * 4));
    bf16_t*       bufA = (bf16_t*)(ws + alloc((size_t)NN * 64 * 2));
    bf16_t*       bufB = (bf16_t*)(ws + alloc((size_t)NN * 64 * 2));

    if (o <= ws_size) {
        // ---- bucketed CSR gather path (bf16 intermediates, dword-lane agg) ----
        zero_gcur_kernel<<<(NBUCK + 255) / 256, 256, 0, stream>>>(gcur);
        bin_kernel<<<(NE + TILE - 1) / TILE, 256, 0, stream>>>(src, dst, gcur, brec);
        bucket_csr_kernel<<<NBUCK, 256, 0, stream>>>(gcur, brec, csr, stA, enA, dis);

        gemm64_f32in_kernel<<<(NN + 63) / 64, 256, 0, stream>>>(x, W1, dis, bufA, NN);
        agg_kernel<<<(NN + 7) / 8, 256, 0, stream>>>(csr, stA, enA, dis,
                                                     (const unsigned int*)bufA, b1,
                                                     (unsigned int*)bufB, NN);

        gemm64_bf16in_kernel<<<(NN + 63) / 64, 256, 0, stream>>>(bufB, W2, dis, bufA, NN);
        agg_kernel<<<(NN + 7) / 8, 256, 0, stream>>>(csr, stA, enA, dis,
                                                     (const unsigned int*)bufA, b2,
                                                     (unsigned int*)bufB, NN);

        decode_kernel<<<((NPOS + NNEG) + 7) / 8, 256, 0, stream>>>(pos, neg,
                                                                   (const unsigned int*)bufB, out);
    } else {
        // ---- fallback: atomic scatter path (f32) ----
        float* fdis = (float*)ws;
        size_t foff = ((size_t)NN * 4 + 255) / 256 * 256;
        float* fA = (float*)(ws + foff);
        float* fB = fA + (size_t)NN * 64;

        init_deg_kernel<<<(NN + 255) / 256, 256, 0, stream>>>(fdis, NN);
        deg_count_kernel<<<(NE + 255) / 256, 256, 0, stream>>>(dst, fdis, NE);
        dis_kernel<<<(NN + 255) / 256, 256, 0, stream>>>(fdis, NN);

        gemm64_f32out_kernel<false><<<(NN + 63) / 64, 256, 0, stream>>>(x, W1, fA, NN);
        selfloop_init_kernel<<<(NN * 16 + 255) / 256, 256, 0, stream>>>(fA, fdis, b1, fB, NN);
        edge_agg_kernel<<<(NE + 3) / 4, 256, 0, stream>>>(src, dst, fdis, fA, fB, NE);

        gemm64_f32out_kernel<true><<<(NN + 63) / 64, 256, 0, stream>>>(fB, W2, fA, NN);
        selfloop_init_kernel<<<(NN * 16 + 255) / 256, 256, 0, stream>>>(fA, fdis, b2, fB, NN);
        edge_agg_kernel<<<(NE + 3) / 4, 256, 0, stream>>>(src, dst, fdis, fA, fB, NE);

        decode_f32_kernel<<<((NPOS + NNEG) + 3) / 4, 256, 0, stream>>>(pos, neg, fB, out);
    }
}